// Round 16
// baseline (5456.269 us; speedup 1.0000x reference)
//
#include <hip/hip_runtime.h>
#include <math.h>

#define N_  2048
#define T_  200
#define D_  16
#define H_  64
#define C2_ 128
#define BM  8
#define NTHR 1024
#define NBLK 256

// X slot: [128][2048] bf16 + 4KB guard gap
#define SLOT_USH ((size_t)C2_ * N_ + 2048)

typedef unsigned short ushort_t;
typedef short bf16x8 __attribute__((ext_vector_type(8)));
typedef float f32x4 __attribute__((ext_vector_type(4)));

// ---- weight blob layout (ushort offsets) ----
#define W_HC 0        // W_h_cur^T  [64][64]  swz8
#define W_HP 4096     // W_h_prev^T [64][64]  swz8
#define W_CC 8192     // W_c_cur^T  [64][64]  swz8
#define W_CP 12288    // W_c_prev^T [64][64]  swz8
#define W_G  16384    // [Wgh^T ; Wgc^T] [128][64] swz8
#define W_R  24576    // R^T [256][64] swz8
#define W_K  40960    // K^T [256][16] swz2  (read from GLOBAL in epiC)
#define W_USH 45056   // then 512 fp32 biases
#define BLOB_BYTES 92160

__device__ __forceinline__ float sig_(float x) {
    return __fdividef(1.0f, 1.0f + __expf(-x));
}
__device__ __forceinline__ float tanh_(float x) {
    float e = __expf(-2.0f * fabsf(x));
    float t = __fdividef(1.0f - e, 1.0f + e);
    return copysignf(t, x);
}
__device__ __forceinline__ ushort_t f2bf(float f) {
    unsigned u = __float_as_uint(f);
    u = (u + 0x7FFFu + ((u >> 16) & 1u)) >> 16;
    return (ushort_t)u;
}
__device__ __forceinline__ float blo(unsigned u){ return __uint_as_float(u << 16); }
__device__ __forceinline__ float bhi(unsigned u){ return __uint_as_float(u & 0xFFFF0000u); }

__device__ __forceinline__ void gload16(const void* g, void* l) {
    __builtin_amdgcn_global_load_lds(
        (const __attribute__((address_space(1))) unsigned int*)g,
        (__attribute__((address_space(3))) unsigned int*)l, 16, 0, 0);
}

// B-fragment load (DEEP: fresh-slot cached; else uncached agent-scope)
template<bool DEEP>
__device__ __forceinline__ bf16x8 ldB(const ushort_t* p) {
    if constexpr (DEEP) {
        return *(const bf16x8*)p;
    } else {
        union { unsigned long long q[2]; bf16x8 v; } u;
        u.q[0] = __hip_atomic_load((const unsigned long long*)p,
                                   __ATOMIC_RELAXED, __HIP_MEMORY_SCOPE_AGENT);
        u.q[1] = __hip_atomic_load(((const unsigned long long*)p) + 1,
                                   __ATOMIC_RELAXED, __HIP_MEMORY_SCOPE_AGENT);
        return u.v;
    }
}

// ---- A (fp32) -> A (bf16); zero all barrier counters (1024 slots) ----
__global__ __launch_bounds__(256) void convert_A_kernel(
    const float* __restrict__ A, ushort_t* __restrict__ Abf,
    unsigned* __restrict__ cnt)
{
    if (blockIdx.x == 0) {
        #pragma unroll
        for (int p = 0; p < 4; p++)
            __hip_atomic_store(cnt + p * 256 + threadIdx.x, 0u,
                               __ATOMIC_RELAXED, __HIP_MEMORY_SCOPE_AGENT);
    }
    size_t i = ((size_t)blockIdx.x * 256 + threadIdx.x) * 4;
    float4 v = *(const float4*)(A + i);
    ushort4 o;
    o.x = f2bf(v.x); o.y = f2bf(v.y); o.z = f2bf(v.z); o.w = f2bf(v.w);
    *(ushort4*)(Abf + i) = o;
}

// ---- pack weights: bf16, transposed, XOR-swizzled 16B chunks ----
__global__ __launch_bounds__(256) void convert_W_kernel(
    const float* __restrict__ Whc, const float* __restrict__ Whp,
    const float* __restrict__ Wcc, const float* __restrict__ Wcp,
    const float* __restrict__ Wgh, const float* __restrict__ Wgc,
    const float* __restrict__ R,   const float* __restrict__ Kw,
    const float* __restrict__ bh,  const float* __restrict__ bc,
    const float* __restrict__ bgh, const float* __restrict__ bgc,
    const float* __restrict__ bl,
    ushort_t* __restrict__ blob)
{
    const int stride = gridDim.x * 256;
    const int gid = blockIdx.x * 256 + threadIdx.x;
    for (int idx = gid; idx < 4096; idx += stride) {
        int k = idx >> 6, c = idx & 63;
        int dst = c * 64 + ((((k >> 3) ^ c) & 7) << 3) + (k & 7);
        blob[W_HC + dst] = f2bf(Whc[idx]);
        blob[W_HP + dst] = f2bf(Whp[idx]);
        blob[W_CC + dst] = f2bf(Wcc[idx]);
        blob[W_CP + dst] = f2bf(Wcp[idx]);
        blob[W_G + dst]        = f2bf(Wgh[idx]);
        blob[W_G + 4096 + dst] = f2bf(Wgc[idx]);
    }
    for (int idx = gid; idx < 16384; idx += stride) {
        int k = idx >> 8, gc = idx & 255;
        int dst = gc * 64 + ((((k >> 3) ^ gc) & 7) << 3) + (k & 7);
        blob[W_R + dst] = f2bf(R[idx]);
    }
    for (int idx = gid; idx < 4096; idx += stride) {
        int d = idx >> 8, gc = idx & 255;
        int dst = gc * 16 + ((((d >> 3) ^ gc) & 1) << 3) + (d & 7);
        blob[W_K + dst] = f2bf(Kw[idx]);
    }
    float* bf = (float*)(blob + W_USH);
    if (gid < 64) { bf[gid] = bh[gid]; bf[64+gid] = bc[gid]; bf[128+gid] = bgh[gid]; bf[192+gid] = bgc[gid]; }
    if (gid < 256) bf[256 + gid] = bl[gid];
}

// ---- Prologue: X_0^T (premultiplied, bf16, slot 0), h_lstm_0, c_lstm_0 ----
__global__ __launch_bounds__(64) void prologue_kernel(
    const float* __restrict__ xin, const float* __restrict__ h0,
    const float* __restrict__ c0,
    const float* __restrict__ Wgh, const float* __restrict__ bgh,
    const float* __restrict__ Wgc, const float* __restrict__ bgc,
    const float* __restrict__ K, const float* __restrict__ R,
    const float* __restrict__ bl,
    ushort_t* __restrict__ Xt, float* __restrict__ hl, float* __restrict__ cl)
{
    const int n = blockIdx.x;
    const int j = threadIdx.x;
    __shared__ float hs[H_], cs[H_], xs[D_];
    hs[j] = h0[n * H_ + j];
    cs[j] = c0[n * H_ + j];
    if (j < D_) xs[j] = xin[(size_t)n * T_ * D_ + j];
    __syncthreads();

    float xh = bgh[j], xc = bgc[j];
    for (int k = 0; k < H_; k++) {
        xh += hs[k] * Wgh[k * H_ + j];
        xc += cs[k] * Wgc[k * H_ + j];
    }
    Xt[(size_t)j * N_ + n]        = f2bf(xh);
    Xt[(size_t)(H_ + j) * N_ + n] = f2bf(xc);

    float zi = bl[j], zf = bl[H_ + j], zg = bl[2 * H_ + j], zo = bl[3 * H_ + j];
    for (int d = 0; d < D_; d++) {
        float xv = xs[d];
        zi += xv * K[d * 256 + j];
        zf += xv * K[d * 256 + 64 + j];
        zg += xv * K[d * 256 + 128 + j];
        zo += xv * K[d * 256 + 192 + j];
    }
    for (int k = 0; k < H_; k++) {
        float hv = hs[k];
        zi += hv * R[k * 256 + j];
        zf += hv * R[k * 256 + 64 + j];
        zg += hv * R[k * 256 + 128 + j];
        zo += hv * R[k * 256 + 192 + j];
    }
    float clv = sig_(zf) * cs[j] + sig_(zi) * tanh_(zg);
    float hlv = sig_(zo) * tanh_(clv);
    cl[n * H_ + j] = clv;
    hl[n * H_ + j] = hlv;
}

// ---- Persistent kernel (R15 GEMM + MFMA epilogues A/B) ----
template<bool DEEP>
__global__ __launch_bounds__(NTHR, 4) void persistent_kernel(
    const ushort_t* __restrict__ Abf,
    ushort_t* __restrict__ Xs,
    const float* __restrict__ hl, const float* __restrict__ clm,
    const float* __restrict__ xin,
    const ushort_t* __restrict__ Wblob,
    float* __restrict__ oh, float* __restrict__ oc,
    unsigned* __restrict__ cnt)
{
    __shared__ __align__(16) ushort_t WL[46080];     // 90 KB weights+biases
    __shared__ __align__(16) ushort_t Alds[BM * N_]; // 32 KB A-panel, chunk-swizzled
    __shared__ __align__(16) float HLs[512], CLs[512], HNs[512], CNs[512];
    __shared__ __align__(16) ushort_t HLb[512], CLb[512], HNb[512], CNb[512];  // bf16 mirrors
    __shared__ __align__(16) ushort_t Gsb[1024];     // tanh(A@X) bf16 [8][128]
    __shared__ __align__(16) float XSs[BM * D_];
    __shared__ __align__(16) float part[4 * BM * C2_];   // 16 KB GEMM partials

    const int tid  = threadIdx.x;
    const int brow = blockIdx.x * BM;
    const int wave = tid >> 6;
    const int lane = tid & 63;

    // barrier tree: root = cnt[0]; group g counter = cnt[32 + g*32]
    unsigned* grpc = cnt + 32 + (blockIdx.x >> 4) * 32;
    unsigned* root = cnt;

    // ---- one-time staging: weights + state ----
    {
        const char* gsrc = (const char*)Wblob;
        char* lbase = (char*)WL;
        for (int i = wave; i < 90; i += 16)
            gload16(gsrc + i * 1024 + lane * 16, lbase + i * 1024);
        if (wave == 0) {
            gload16((const char*)(hl + (size_t)brow * H_) + lane * 16, (char*)HLs);
            gload16((const char*)(hl + (size_t)brow * H_) + 1024 + lane * 16, (char*)HLs + 1024);
        }
        if (wave == 1) {
            gload16((const char*)(clm + (size_t)brow * H_) + lane * 16, (char*)CLs);
            gload16((const char*)(clm + (size_t)brow * H_) + 1024 + lane * 16, (char*)CLs + 1024);
        }
    }
    // ---- one-time: A-panel -> LDS, 16B-chunk XOR swizzle ----
    for (int idx = tid; idx < BM * 256; idx += NTHR) {
        int row = idx >> 8;
        int kc  = idx & 255;
        bf16x8 v = *(const bf16x8*)(Abf + (size_t)(brow + row) * N_ + kc * 8);
        int swzc = (kc & ~7) | ((kc ^ row) & 7);
        *(bf16x8*)((char*)Alds + row * 4096 + swzc * 16) = v;
    }
    __syncthreads();
    // ---- one-time: bf16 mirrors of initial state ----
    if (tid < 512) { HLb[tid] = f2bf(HLs[tid]); CLb[tid] = f2bf(CLs[tid]); }
    __syncthreads();

    const float* BL = (const float*)(WL + W_USH);

    for (int t = 0; t < T_; t++) {
        const ushort_t* Xc = Xs + (size_t)(DEEP ? t : (t & 1)) * SLOT_USH;
        ushort_t*       Xn = Xs + (size_t)(DEEP ? (t + 1) : ((t + 1) & 1)) * SLOT_USH;

        // prefetch x_{t+1} (drains at next barrier)
        if (t + 1 < T_ && wave == 7 && lane < 32) {
            const float* g = xin + (size_t)(brow + (lane >> 2)) * (T_ * D_)
                                 + (size_t)(t + 1) * D_ + (lane & 3) * 4;
            gload16(g, (char*)XSs);
        }

        // ---- GEMM: 16 waves = 4 col-tiles x 4 k-quarters (block-rotated);
        //      two-pass burst-16 B-loads; A from LDS ----
        {
            const int ct = (wave & 3) * 32;
            const int kq = ((((wave >> 2) + blockIdx.x) & 3)) * 512;
            const int fr = lane & 15;
            const int kg = lane >> 4;
            const int arow = fr & 7;
            const int kcb = (kq >> 3) + kg;
            const ushort_t* Bp0 = Xc + (size_t)(ct + fr) * N_ + kq + kg * 8;
            const ushort_t* Bp1 = Bp0 + (size_t)16 * N_;
            f32x4 acc0 = {0.f, 0.f, 0.f, 0.f}, acc1 = {0.f, 0.f, 0.f, 0.f};

            bf16x8 rb[16];
            #pragma unroll
            for (int kk = 0; kk < 16; kk++) rb[kk] = ldB<DEEP>(Bp0 + kk * 32);
            #pragma unroll
            for (int kk = 0; kk < 16; kk++) {
                const int kc  = kcb + kk * 4;
                const int swzc = (kc & ~7) | ((kc ^ arow) & 7);
                bf16x8 a = *(const bf16x8*)((const char*)Alds + arow * 4096 + swzc * 16);
                acc0 = __builtin_amdgcn_mfma_f32_16x16x32_bf16(a, rb[kk], acc0, 0, 0, 0);
            }
            #pragma unroll
            for (int kk = 0; kk < 16; kk++) rb[kk] = ldB<DEEP>(Bp1 + kk * 32);
            #pragma unroll
            for (int kk = 0; kk < 16; kk++) {
                const int kc  = kcb + kk * 4;
                const int swzc = (kc & ~7) | ((kc ^ arow) & 7);
                bf16x8 a = *(const bf16x8*)((const char*)Alds + arow * 4096 + swzc * 16);
                acc1 = __builtin_amdgcn_mfma_f32_16x16x32_bf16(a, rb[kk], acc1, 0, 0, 0);
            }
            if (kg < 2) {
                float* pp = &part[(wave >> 2) * (BM * C2_) + ct];
                const int rb4 = kg * 4;
                #pragma unroll
                for (int r = 0; r < 4; r++) {
                    pp[(rb4 + r) * C2_ + fr]      = acc0[r];
                    pp[(rb4 + r) * C2_ + 16 + fr] = acc1[r];
                }
            }
        }
        __syncthreads();

        // ---- reduce 4 k-partials + tanh -> Gsb (bf16) ----
        Gsb[tid] = f2bf(tanh_(part[tid] + part[1024 + tid] + part[2048 + tid] + part[3072 + tid]));
        __syncthreads();

        // ---- epilogue A (MFMA, waves 0-7): h_new / c_new ----
        if (wave < 8) {
            const int p  = wave >> 2;        // 0=h, 1=c
            const int ct = wave & 3;
            const int fr = lane & 15;
            const int kg = lane >> 4;
            const int c  = ct * 16 + fr;     // 0..63
            const int r7 = fr & 7;
            const int swzc = c & 7;
            const ushort_t* Sb = p ? CLb : HLb;
            const ushort_t* Wc = &WL[p ? W_CC : W_HC];
            const ushort_t* Wp = &WL[p ? W_CP : W_HP];
            bf16x8 a1a = *(const bf16x8*)(Sb + r7 * 64 + kg * 8);
            bf16x8 a1b = *(const bf16x8*)(Sb + r7 * 64 + 32 + kg * 8);
            bf16x8 a2a = *(const bf16x8*)(Gsb + r7 * 128 + p * 64 + kg * 8);
            bf16x8 a2b = *(const bf16x8*)(Gsb + r7 * 128 + p * 64 + 32 + kg * 8);
            bf16x8 b1a = *(const bf16x8*)(Wc + c * 64 + ((kg ^ swzc) & 7) * 8);
            bf16x8 b1b = *(const bf16x8*)(Wc + c * 64 + (((4 + kg) ^ swzc) & 7) * 8);
            bf16x8 b2a = *(const bf16x8*)(Wp + c * 64 + ((kg ^ swzc) & 7) * 8);
            bf16x8 b2b = *(const bf16x8*)(Wp + c * 64 + (((4 + kg) ^ swzc) & 7) * 8);
            const float bias = BL[p * 64 + c];
            f32x4 acc = {bias, bias, bias, bias};
            acc = __builtin_amdgcn_mfma_f32_16x16x32_bf16(a1a, b1a, acc, 0, 0, 0);
            acc = __builtin_amdgcn_mfma_f32_16x16x32_bf16(a1b, b1b, acc, 0, 0, 0);
            acc = __builtin_amdgcn_mfma_f32_16x16x32_bf16(a2a, b2a, acc, 0, 0, 0);
            acc = __builtin_amdgcn_mfma_f32_16x16x32_bf16(a2b, b2b, acc, 0, 0, 0);
            if (kg < 2) {
                float* Sf     = p ? CNs : HNs;
                ushort_t* Sb2 = p ? CNb : HNb;
                float* op     = p ? oc : oh;
                #pragma unroll
                for (int r = 0; r < 4; r++) {
                    const int row = kg * 4 + r;
                    float v = sig_(acc[r]);
                    Sf[row * 64 + c]  = v;
                    Sb2[row * 64 + c] = f2bf(v);
                    op[(size_t)(brow + row) * (T_ * H_) + (size_t)t * H_ + c] = v;
                }
            }
        }

        if (t + 1 == T_) break;
        __syncthreads();

        // ---- epilogue B (MFMA, waves 8-15): X_{t+1} premultiplied, direct store ----
        if (wave >= 8) {
            const int jt = wave - 8;         // 0..7
            const int fr = lane & 15;
            const int kg = lane >> 4;
            const int j  = jt * 16 + fr;     // 0..127
            const int r7 = fr & 7;
            const int swzj = j & 7;
            const ushort_t* Sb = (jt < 4) ? HNb : CNb;
            bf16x8 a1 = *(const bf16x8*)(Sb + r7 * 64 + kg * 8);
            bf16x8 a2 = *(const bf16x8*)(Sb + r7 * 64 + 32 + kg * 8);
            bf16x8 b1 = *(const bf16x8*)(&WL[W_G] + j * 64 + ((kg ^ swzj) & 7) * 8);
            bf16x8 b2 = *(const bf16x8*)(&WL[W_G] + j * 64 + (((4 + kg) ^ swzj) & 7) * 8);
            const float bias = BL[128 + j];
            f32x4 acc = {bias, bias, bias, bias};
            acc = __builtin_amdgcn_mfma_f32_16x16x32_bf16(a1, b1, acc, 0, 0, 0);
            acc = __builtin_amdgcn_mfma_f32_16x16x32_bf16(a2, b2, acc, 0, 0, 0);
            if (kg < 2) {
                unsigned long long v =
                      (unsigned long long)f2bf(acc[0])
                    | ((unsigned long long)f2bf(acc[1]) << 16)
                    | ((unsigned long long)f2bf(acc[2]) << 32)
                    | ((unsigned long long)f2bf(acc[3]) << 48);
                __hip_atomic_store((unsigned long long*)(Xn + (size_t)j * N_ + brow + kg * 4),
                                   v, __ATOMIC_RELAXED, __HIP_MEMORY_SCOPE_AGENT);
            }
        }
        __syncthreads();   // drains X stores (vmcnt 0 before s_barrier)

        // ---- arrive (2-level tree), then hide latency under epilogue C ----
        if (tid == 0) {
            unsigned old = __hip_atomic_fetch_add(grpc, 1u, __ATOMIC_RELAXED,
                                                  __HIP_MEMORY_SCOPE_AGENT);
            if (old == 16u * (unsigned)(t + 1) - 1u)
                __hip_atomic_fetch_add(root, 1u, __ATOMIC_RELAXED,
                                       __HIP_MEMORY_SCOPE_AGENT);
        }

        // ---- epilogue C: h_lstm/c_lstm for t+1 -> HLs/CLs (+bf16 mirrors) ----
        if (tid < 512) {
            const int c = tid & 63;
            const int r = tid >> 6;
            float z[4];
            #pragma unroll
            for (int g = 0; g < 4; g++) z[g] = BL[256 + g * 64 + c];
            const int swz1 = c & 1, swz = c & 7;
            #pragma unroll
            for (int g = 0; g < 4; g++) {
                const ushort_t* Krow = Wblob + W_K + (g * 64 + c) * 16;  // GLOBAL (L2-hot)
                #pragma unroll
                for (int dd = 0; dd < 2; dd++) {
                    const int pc = ((dd ^ swz1) << 3);
                    uint4 w = *(const uint4*)&Krow[pc];
                    const unsigned* u = (const unsigned*)&w;
                    const float* xb = &XSs[r * 16 + dd * 8];
                    #pragma unroll
                    for (int q = 0; q < 4; q++)
                        z[g] += blo(u[q]) * xb[2*q] + bhi(u[q]) * xb[2*q+1];
                }
                const ushort_t* Rrow = &WL[W_R + (g * 64 + c) * 64];
                #pragma unroll
                for (int kk = 0; kk < 8; kk++) {
                    const int pc = ((kk ^ swz) << 3);
                    uint4 w = *(const uint4*)&Rrow[pc];
                    const unsigned* u = (const unsigned*)&w;
                    const float* hb = &HNs[r * 64 + kk * 8];
                    #pragma unroll
                    for (int q = 0; q < 4; q++)
                        z[g] += blo(u[q]) * hb[2*q] + bhi(u[q]) * hb[2*q+1];
                }
            }
            float clv = sig_(z[1]) * CNs[r * 64 + c] + sig_(z[0]) * tanh_(z[2]);
            float hlv = sig_(z[3]) * tanh_(clv);
            CLs[r * 64 + c] = clv;
            HLs[r * 64 + c] = hlv;
            CLb[r * 64 + c] = f2bf(clv);
            HLb[r * 64 + c] = f2bf(hlv);
        }

        // ---- poll root ----
        if (tid == 0) {
            const unsigned target = 16u * (unsigned)(t + 1);
            while (__hip_atomic_load(root, __ATOMIC_RELAXED, __HIP_MEMORY_SCOPE_AGENT) < target)
                __builtin_amdgcn_s_sleep(1);
        }
        __syncthreads();
        asm volatile("" ::: "memory");
    }
}

extern "C" void kernel_launch(void* const* d_in, const int* in_sizes, int n_in,
                              void* d_out, int out_size, void* d_ws, size_t ws_size,
                              hipStream_t stream) {
    const float* xin = (const float*)d_in[0];
    const float* h0  = (const float*)d_in[1];
    const float* c0  = (const float*)d_in[2];
    const float* A   = (const float*)d_in[3];
    const float* Wgh = (const float*)d_in[4];
    const float* bgh = (const float*)d_in[5];
    const float* Wgc = (const float*)d_in[6];
    const float* bgc = (const float*)d_in[7];
    const float* Whc = (const float*)d_in[8];
    const float* Whp = (const float*)d_in[9];
    const float* bh  = (const float*)d_in[10];
    const float* Wcc = (const float*)d_in[11];
    const float* Wcp = (const float*)d_in[12];
    const float* bc  = (const float*)d_in[13];
    const float* K   = (const float*)d_in[14];
    const float* R   = (const float*)d_in[15];
    const float* bl  = (const float*)d_in[16];

    const size_t fixed = (size_t)N_ * N_ * 2
                       + (size_t)N_ * H_ * 4 * 2
                       + BLOB_BYTES + 4096;
    const size_t slot_bytes = SLOT_USH * 2;
    const bool deep = ws_size >= fixed + (size_t)(T_ + 1) * slot_bytes;
    const int nslots = deep ? (T_ + 1) : 2;

    char* w = (char*)d_ws;
    ushort_t* Abf  = (ushort_t*)w;  w += (size_t)N_ * N_ * 2;
    ushort_t* Xs   = (ushort_t*)w;  w += (size_t)nslots * slot_bytes;
    float* hl      = (float*)w;     w += (size_t)N_ * H_ * 4;
    float* cl      = (float*)w;     w += (size_t)N_ * H_ * 4;
    ushort_t* blob = (ushort_t*)w;  w += BLOB_BYTES;
    unsigned* cnt  = (unsigned*)w;  w += 4096;

    float* oh = (float*)d_out;
    float* oc = oh + (size_t)N_ * T_ * H_;

    convert_A_kernel<<<(N_ * N_) / (256 * 4), 256, 0, stream>>>(A, Abf, cnt);
    convert_W_kernel<<<16, 256, 0, stream>>>(Whc, Whp, Wcc, Wcp, Wgh, Wgc, R, K,
                                             bh, bc, bgh, bgc, bl, blob);
    prologue_kernel<<<N_, 64, 0, stream>>>(xin, h0, c0, Wgh, bgh, Wgc, bgc,
                                           K, R, bl, Xs, hl, cl);

    void* args[] = { (void*)&Abf, (void*)&Xs, (void*)&hl, (void*)&cl,
                     (void*)&xin, (void*)&blob, (void*)&oh, (void*)&oc, (void*)&cnt };
    if (deep)
        hipLaunchCooperativeKernel((const void*)persistent_kernel<true>,
                                   dim3(NBLK), dim3(NTHR), args, 0, stream);
    else
        hipLaunchCooperativeKernel((const void*)persistent_kernel<false>,
                                   dim3(NBLK), dim3(NTHR), args, 0, stream);
}